// Round 3
// baseline (268.075 us; speedup 1.0000x reference)
//
#include <hip/hip_runtime.h>
#include <math.h>

#define B_DIM 128
#define N_DIM 512
#define D_DIM 512
#define H_DIM 256
#define K_SEL 8

typedef __bf16 bf16x8 __attribute__((ext_vector_type(8)));
typedef float  f32x4  __attribute__((ext_vector_type(4)));

// ---------------- Kernel 0: prep W1 -> transposed bf16 3-way splits ----------------
// W1 (512x256 f32, [k][c]) -> w1t_{h,m,l} (256x512 bf16, [c][k]) stored in d_out scratch.
// x = h + m + l + eps, |eps| <= 2^-27 |x| (RNE at each level; residuals exact in fp32).
__global__ __launch_bounds__(256) void prep_w1_kernel(
    const float* __restrict__ W1,
    __bf16* __restrict__ w1t_h,
    __bf16* __restrict__ w1t_m,
    __bf16* __restrict__ w1t_l)
{
    const int c = blockIdx.x;      // 256 cols
    const int t = threadIdx.x;     // 256 threads over k
    #pragma unroll
    for (int kk = 0; kk < D_DIM; kk += 256) {
        int k = kk + t;
        float x = W1[(size_t)k * H_DIM + c];
        __bf16 h = (__bf16)x;
        float r1 = x - (float)h;
        __bf16 m = (__bf16)r1;
        float r2 = r1 - (float)m;
        __bf16 l = (__bf16)r2;
        w1t_h[(size_t)c * D_DIM + k] = h;
        w1t_m[(size_t)c * D_DIM + k] = m;
        w1t_l[(size_t)c * D_DIM + k] = l;
    }
}

// ---------------- Kernel 1: bf16x3-split MFMA scorer ----------------
// Grid: 1024 WGs x 512 threads. WG = 64 rows x 256 cols (full H).
// 8 waves, 2M x 4N; per-wave 32x64 = 2x4 frags of mfma_f32_16x16x32_bf16.
// fp32 accuracy via 6 products: hh + hm + mh + hl + mm + lh (drop <= 2^-27 terms).
__global__ __launch_bounds__(512) void fused_scorer_mfma(
    const float* __restrict__ X,           // (65536, 512)
    const __bf16* __restrict__ w1t_h,      // (256, 512)
    const __bf16* __restrict__ w1t_m,      // (256, 512)
    const __bf16* __restrict__ w1t_l,      // (256, 512)
    const float* __restrict__ b1,          // (256)
    const float* __restrict__ W2,          // (256)
    const float* __restrict__ b2p,         // scalar
    const float* __restrict__ base_logits, // (512)
    float* __restrict__ logits)            // (65536)
{
    __shared__ float red[4][64];
    const int tid  = threadIdx.x;
    const int lane = tid & 63;
    const int wave = tid >> 6;           // 0..7
    const int wm0  = (wave >> 2) * 32;   // 0 / 32
    const int wn0  = (wave & 3) * 64;    // 0,64,128,192
    const int l15  = lane & 15;
    const int lg   = lane >> 4;          // 0..3 (k-group)
    const int row0 = blockIdx.x * 64;

    f32x4 acc[2][4];
    #pragma unroll
    for (int mi = 0; mi < 2; ++mi)
        #pragma unroll
        for (int nj = 0; nj < 4; ++nj)
            acc[mi][nj] = (f32x4){0.f, 0.f, 0.f, 0.f};

    // per-lane epilogue constants (cols this lane owns)
    float b1v[4], w2v[4];
    #pragma unroll
    for (int nj = 0; nj < 4; ++nj) {
        int col = wn0 + nj * 16 + l15;
        b1v[nj] = b1[col];
        w2v[nj] = W2[col];
    }

    for (int ks = 0; ks < 16; ++ks) {
        const int k0 = ks * 32;
        bf16x8 ah[2], am[2], al[2];

        // A loads + 3-way split (in-register)
        #pragma unroll
        for (int mi = 0; mi < 2; ++mi) {
            const float* xp = X + (size_t)(row0 + wm0 + mi * 16 + l15) * D_DIM + k0 + lg * 8;
            float4 av0 = *reinterpret_cast<const float4*>(xp);
            float4 av1 = *reinterpret_cast<const float4*>(xp + 4);
            float xr[8] = {av0.x, av0.y, av0.z, av0.w, av1.x, av1.y, av1.z, av1.w};
            #pragma unroll
            for (int e = 0; e < 8; ++e) {
                __bf16 h = (__bf16)xr[e];
                float r1 = xr[e] - (float)h;
                __bf16 m = (__bf16)r1;
                float r2 = r1 - (float)m;
                ah[mi][e] = h;
                am[mi][e] = m;
                al[mi][e] = (__bf16)r2;
            }
        }
        // B frags: lane l -> col = wn0+nj*16+l15, k = k0 + lg*8 .. +7 (contiguous 16B)
        bf16x8 bh[4], bm[4], bl[4];
        #pragma unroll
        for (int nj = 0; nj < 4; ++nj) {
            size_t off = (size_t)(wn0 + nj * 16 + l15) * D_DIM + k0 + lg * 8;
            bh[nj] = *reinterpret_cast<const bf16x8*>(w1t_h + off);
            bm[nj] = *reinterpret_cast<const bf16x8*>(w1t_m + off);
            bl[nj] = *reinterpret_cast<const bf16x8*>(w1t_l + off);
        }
        // 48 MFMAs: 6 products into the same accumulator
        #pragma unroll
        for (int mi = 0; mi < 2; ++mi)
            #pragma unroll
            for (int nj = 0; nj < 4; ++nj) {
                acc[mi][nj] = __builtin_amdgcn_mfma_f32_16x16x32_bf16(ah[mi], bh[nj], acc[mi][nj], 0, 0, 0);
                acc[mi][nj] = __builtin_amdgcn_mfma_f32_16x16x32_bf16(ah[mi], bm[nj], acc[mi][nj], 0, 0, 0);
                acc[mi][nj] = __builtin_amdgcn_mfma_f32_16x16x32_bf16(am[mi], bh[nj], acc[mi][nj], 0, 0, 0);
                acc[mi][nj] = __builtin_amdgcn_mfma_f32_16x16x32_bf16(ah[mi], bl[nj], acc[mi][nj], 0, 0, 0);
                acc[mi][nj] = __builtin_amdgcn_mfma_f32_16x16x32_bf16(am[mi], bm[nj], acc[mi][nj], 0, 0, 0);
                acc[mi][nj] = __builtin_amdgcn_mfma_f32_16x16x32_bf16(al[mi], bh[nj], acc[mi][nj], 0, 0, 0);
            }
    }

    // Epilogue: z = acc + b1 ; g = exact GELU(z) ; partial logit = sum_n g*W2
    float part[2][4];
    #pragma unroll
    for (int mi = 0; mi < 2; ++mi)
        #pragma unroll
        for (int r = 0; r < 4; ++r)
            part[mi][r] = 0.f;
    #pragma unroll
    for (int mi = 0; mi < 2; ++mi)
        #pragma unroll
        for (int nj = 0; nj < 4; ++nj)
            #pragma unroll
            for (int r = 0; r < 4; ++r) {
                float z = acc[mi][nj][r] + b1v[nj];
                float g = 0.5f * z * (1.0f + erff(z * 0.70710678118654752440f));
                part[mi][r] = fmaf(g, w2v[nj], part[mi][r]);
            }
    // reduce over the 16 cols in this lane-group (xor within width 16)
    #pragma unroll
    for (int mi = 0; mi < 2; ++mi)
        #pragma unroll
        for (int r = 0; r < 4; ++r) {
            float v = part[mi][r];
            v += __shfl_xor(v, 1, 16);
            v += __shfl_xor(v, 2, 16);
            v += __shfl_xor(v, 4, 16);
            v += __shfl_xor(v, 8, 16);
            if (l15 == 0)
                red[wave & 3][wm0 + mi * 16 + lg * 4 + r] = v;
        }
    __syncthreads();
    if (tid < 64) {
        float s = red[0][tid] + red[1][tid] + red[2][tid] + red[3][tid];
        int grow = row0 + tid;
        logits[grow] = s + b2p[0] + base_logits[grow & (N_DIM - 1)];
    }
}

// ---------------- Kernel 2: softmax + top-8 + mask/importance/indices ----------------
__global__ __launch_bounds__(256) void softmax_topk_kernel(
    const float* __restrict__ logits,     // (B, N) — in d_out scratch
    float* __restrict__ out_mask,         // (B, N)
    float* __restrict__ out_importance,   // (B, N)
    float* __restrict__ out_indices)      // (B, K) as float
{
    const int b = blockIdx.x;
    const int tid = threadIdx.x;
    __shared__ float probs[N_DIM];
    __shared__ float redf[4];
    __shared__ int   redi[4];
    __shared__ int   sel_idx[K_SEL];

    float l0 = logits[b * N_DIM + tid];
    float l1 = logits[b * N_DIM + tid + 256];

    float m = fmaxf(l0, l1);
    #pragma unroll
    for (int s = 32; s >= 1; s >>= 1) m = fmaxf(m, __shfl_xor(m, s, 64));
    if ((tid & 63) == 0) redf[tid >> 6] = m;
    __syncthreads();
    float gm = fmaxf(fmaxf(redf[0], redf[1]), fmaxf(redf[2], redf[3]));
    __syncthreads();

    float e0 = expf(l0 - gm), e1 = expf(l1 - gm);
    float ssum = e0 + e1;
    #pragma unroll
    for (int s = 32; s >= 1; s >>= 1) ssum += __shfl_xor(ssum, s, 64);
    if ((tid & 63) == 0) redf[tid >> 6] = ssum;
    __syncthreads();
    float denom = redf[0] + redf[1] + redf[2] + redf[3];
    float p0 = e0 / denom, p1 = e1 / denom;
    probs[tid] = p0;
    probs[tid + 256] = p1;
    out_importance[b * N_DIM + tid] = p0;
    out_importance[b * N_DIM + tid + 256] = p1;
    __syncthreads();

    for (int it = 0; it < K_SEL; ++it) {
        float v0 = probs[tid]; int i0 = tid;
        float v1 = probs[tid + 256];
        if (v1 > v0) { v0 = v1; i0 = tid + 256; }
        #pragma unroll
        for (int s = 32; s >= 1; s >>= 1) {
            float ov = __shfl_xor(v0, s, 64);
            int   oi = __shfl_xor(i0, s, 64);
            if (ov > v0 || (ov == v0 && oi < i0)) { v0 = ov; i0 = oi; }
        }
        if ((tid & 63) == 0) { redf[tid >> 6] = v0; redi[tid >> 6] = i0; }
        __syncthreads();
        if (tid == 0) {
            float bv = redf[0]; int bi = redi[0];
            for (int w = 1; w < 4; ++w)
                if (redf[w] > bv || (redf[w] == bv && redi[w] < bi)) { bv = redf[w]; bi = redi[w]; }
            sel_idx[it] = bi;
            probs[bi] = -1.0f;
        }
        __syncthreads();
    }

    float mk0 = 0.f, mk1 = 0.f;
    #pragma unroll
    for (int i = 0; i < K_SEL; ++i) {
        if (sel_idx[i] == tid)       mk0 = 1.f;
        if (sel_idx[i] == tid + 256) mk1 = 1.f;
    }
    out_mask[b * N_DIM + tid] = mk0;
    out_mask[b * N_DIM + tid + 256] = mk1;

    if (tid < K_SEL) out_indices[b * K_SEL + tid] = (float)sel_idx[tid];
}

// ---------------- Kernel 3: gather selected rows (overwrites scratch region last) ------
__global__ __launch_bounds__(256) void gather_kernel(
    const float* __restrict__ X,           // (B, N, D)
    const float* __restrict__ out_indices, // (B, K) as float
    float* __restrict__ out_selected)      // (B, K, D)
{
    const int b = blockIdx.x;
    const int tid = threadIdx.x;
    __shared__ int sel[K_SEL];
    if (tid < K_SEL) sel[tid] = (int)out_indices[b * K_SEL + tid];
    __syncthreads();
    #pragma unroll
    for (int i = 0; i < 4; ++i) {
        int f = tid + 256 * i;
        int ki = f >> 7;       // 128 float4 per row
        int c4 = f & 127;
        float4 v = reinterpret_cast<const float4*>(
            X + ((size_t)b * N_DIM + sel[ki]) * D_DIM)[c4];
        reinterpret_cast<float4*>(
            out_selected + ((size_t)b * K_SEL + ki) * D_DIM)[c4] = v;
    }
}

extern "C" void kernel_launch(void* const* d_in, const int* in_sizes, int n_in,
                              void* d_out, int out_size, void* d_ws, size_t ws_size,
                              hipStream_t stream) {
    const float* X           = (const float*)d_in[0];
    const float* W1          = (const float*)d_in[1];
    const float* b1          = (const float*)d_in[2];
    const float* W2          = (const float*)d_in[3];
    const float* b2          = (const float*)d_in[4];
    const float* base_logits = (const float*)d_in[5];

    float* out            = (float*)d_out;
    float* out_selected   = out;                                  // 128*8*512 = 524288
    float* out_mask       = out_selected + B_DIM * K_SEL * D_DIM; // 128*512
    float* out_importance = out_mask + B_DIM * N_DIM;             // 128*512
    float* out_indices    = out_importance + B_DIM * N_DIM;       // 128*8

    // Scratch lives INSIDE out_selected's 524288-float region (gather overwrites it last):
    //   [0      .. 65536)  logits (f32)
    //   [65536  .. 131072) w1t_h  (131072 bf16)
    //   [131072 .. 196608) w1t_m
    //   [196608 .. 262144) w1t_l
    float*  logits = out_selected;
    __bf16* w1t_h  = (__bf16*)(out_selected + 65536);
    __bf16* w1t_m  = (__bf16*)(out_selected + 131072);
    __bf16* w1t_l  = (__bf16*)(out_selected + 196608);

    hipLaunchKernelGGL(prep_w1_kernel, dim3(H_DIM), dim3(256), 0, stream,
                       W1, w1t_h, w1t_m, w1t_l);
    hipLaunchKernelGGL(fused_scorer_mfma, dim3((B_DIM * N_DIM) / 64), dim3(512), 0, stream,
                       X, w1t_h, w1t_m, w1t_l, b1, W2, b2, base_logits, logits);
    hipLaunchKernelGGL(softmax_topk_kernel, dim3(B_DIM), dim3(256), 0, stream,
                       logits, out_mask, out_importance, out_indices);
    hipLaunchKernelGGL(gather_kernel, dim3(B_DIM), dim3(256), 0, stream,
                       X, out_indices, out_selected);
}

// Round 4
// 120.740 us; speedup vs baseline: 2.2203x; 2.2203x over previous
//
#include <hip/hip_runtime.h>
#include <math.h>

#define B_DIM 128
#define N_DIM 512
#define D_DIM 512
#define H_DIM 256
#define K_SEL 8

typedef __bf16 bf16x4 __attribute__((ext_vector_type(4)));
typedef __bf16 bf16x8 __attribute__((ext_vector_type(8)));
typedef float  f32x4  __attribute__((ext_vector_type(4)));

__device__ __forceinline__ void gload_lds16(const void* g, void* l) {
    __builtin_amdgcn_global_load_lds((const __attribute__((address_space(1))) void*)g,
                                     (__attribute__((address_space(3))) void*)l, 16, 0, 0);
}

// ---------------- Kernel 0: prep W1 -> transposed bf16 3-way splits ----------------
__global__ __launch_bounds__(256) void prep_w1_kernel(
    const float* __restrict__ W1,
    __bf16* __restrict__ w1t_h,
    __bf16* __restrict__ w1t_m,
    __bf16* __restrict__ w1t_l)
{
    const int c = blockIdx.x;      // 256 cols
    const int t = threadIdx.x;     // 256 threads over k
    #pragma unroll
    for (int kk = 0; kk < D_DIM; kk += 256) {
        int k = kk + t;
        float x = W1[(size_t)k * H_DIM + c];
        __bf16 h = (__bf16)x;
        float r1 = x - (float)h;
        __bf16 m = (__bf16)r1;
        float r2 = r1 - (float)m;
        __bf16 l = (__bf16)r2;
        w1t_h[(size_t)c * D_DIM + k] = h;
        w1t_m[(size_t)c * D_DIM + k] = m;
        w1t_l[(size_t)c * D_DIM + k] = l;
    }
}

// ---------------- Kernel 1: bf16x3-split MFMA scorer, LDS-pipelined ----------------
// Grid: 512 WGs x 512 threads. WG = 128 rows x 256 cols. 8 waves 2Mx4N, per-wave 64x64.
// A: reg-staged (load k+2 ahead) -> split once per WG -> ds_write dbuf LDS.
// B: global_load_lds width-16 into dbuf LDS ([col][32k] => wave-uniform base + lane*16).
__global__ __launch_bounds__(512, 2) void fused_scorer_mfma(
    const float* __restrict__ X,           // (65536, 512)
    const __bf16* __restrict__ w1t_h,      // (256, 512)
    const __bf16* __restrict__ w1t_m,
    const __bf16* __restrict__ w1t_l,
    const float* __restrict__ b1,          // (256)
    const float* __restrict__ W2,          // (256)
    const float* __restrict__ b2p,         // scalar
    const float* __restrict__ base_logits, // (512)
    float* __restrict__ logits)            // (65536)
{
    __shared__ __bf16 Ah[2][128][32], Am[2][128][32], Al[2][128][32]; // 48 KB
    __shared__ __bf16 Bh[2][256][32], Bm[2][256][32], Bl[2][256][32]; // 96 KB
    __shared__ float red[4][128];                                     // 2 KB

    const int tid  = threadIdx.x;
    const int lane = tid & 63;
    const int wave = tid >> 6;           // 0..7
    const int wm   = (wave >> 2) << 6;   // 0 / 64
    const int wn   = (wave & 3) << 6;    // 0,64,128,192
    const int l15  = lane & 15;
    const int lg   = lane >> 4;          // 0..3
    const int row0 = blockIdx.x * 128;

    // A staging map: thread -> rows (tid>>3) and (tid>>3)+64, k-quad (tid&7)*4
    const float* xp0 = X + (size_t)(row0 + (tid >> 3)) * D_DIM + (tid & 7) * 4;
    const float* xp1 = xp0 + (size_t)64 * D_DIM;
    // B staging map: thread -> col (tid>>2) (+128), 16B chunk (tid&3)*8
    const int bc = tid >> 2;
    const int bk = (tid & 3) * 8;

    f32x4 acc[4][4];
    #pragma unroll
    for (int mi = 0; mi < 4; ++mi)
        #pragma unroll
        for (int nj = 0; nj < 4; ++nj)
            acc[mi][nj] = (f32x4){0.f, 0.f, 0.f, 0.f};

    float b1v[4], w2v[4];
    #pragma unroll
    for (int nj = 0; nj < 4; ++nj) {
        int col = wn + nj * 16 + l15;
        b1v[nj] = b1[col];
        w2v[nj] = W2[col];
    }

    // split 8 floats -> bf16 h/m/l, ds_write to A buf (byte offsets tid*8 and +4096)
    auto split_write = [&](int buf, float4 va, float4 vb) {
        float e[8] = {va.x, va.y, va.z, va.w, vb.x, vb.y, vb.z, vb.w};
        #pragma unroll
        for (int q = 0; q < 2; ++q) {
            bf16x4 hh, mm, ll;
            #pragma unroll
            for (int j = 0; j < 4; ++j) {
                float x = e[q * 4 + j];
                __bf16 h = (__bf16)x;
                float r1 = x - (float)h;
                __bf16 m = (__bf16)r1;
                float r2 = r1 - (float)m;
                hh[j] = h; mm[j] = m; ll[j] = (__bf16)r2;
            }
            int off = tid * 4 + q * 2048;   // element offset
            *reinterpret_cast<bf16x4*>(&Ah[buf][0][0] + off) = hh;
            *reinterpret_cast<bf16x4*>(&Am[buf][0][0] + off) = mm;
            *reinterpret_cast<bf16x4*>(&Al[buf][0][0] + off) = ll;
        }
    };
    auto stage_b = [&](int buf, int kc) {
        size_t so  = (size_t)bc * D_DIM + kc + bk;
        size_t so2 = (size_t)(bc + 128) * D_DIM + kc + bk;
        gload_lds16(w1t_h + so,  &Bh[buf][bc][bk]);
        gload_lds16(w1t_h + so2, &Bh[buf][bc + 128][bk]);
        gload_lds16(w1t_m + so,  &Bm[buf][bc][bk]);
        gload_lds16(w1t_m + so2, &Bm[buf][bc + 128][bk]);
        gload_lds16(w1t_l + so,  &Bl[buf][bc][bk]);
        gload_lds16(w1t_l + so2, &Bl[buf][bc + 128][bk]);
    };

    // ---- prologue: stage k-step 0; issue xraw(1) ----
    float4 xa = *reinterpret_cast<const float4*>(xp0);
    float4 xb = *reinterpret_cast<const float4*>(xp1);
    stage_b(0, 0);
    split_write(0, xa, xb);
    xa = *reinterpret_cast<const float4*>(xp0 + 32);
    xb = *reinterpret_cast<const float4*>(xp1 + 32);
    __syncthreads();

    for (int ks = 0; ks < 16; ++ks) {
        const int buf = ks & 1, nbuf = buf ^ 1;
        // stage B(ks+1) early (DMA, lands under the MFMA block)
        stage_b(nbuf, ((ks + 1) * 32) & 511);
        // split xraw(ks+1) -> A[nbuf], then re-issue xraw(ks+2)
        split_write(nbuf, xa, xb);
        const int k2 = ((ks + 2) * 32) & 511;
        xa = *reinterpret_cast<const float4*>(xp0 + k2);
        xb = *reinterpret_cast<const float4*>(xp1 + k2);
        // fragments for this k-step
        bf16x8 fah[4], fam[4], fal[4], fbh[4], fbm[4], fbl[4];
        #pragma unroll
        for (int mi = 0; mi < 4; ++mi) {
            int r = wm + mi * 16 + l15;
            fah[mi] = *reinterpret_cast<const bf16x8*>(&Ah[buf][r][lg * 8]);
            fam[mi] = *reinterpret_cast<const bf16x8*>(&Am[buf][r][lg * 8]);
            fal[mi] = *reinterpret_cast<const bf16x8*>(&Al[buf][r][lg * 8]);
        }
        #pragma unroll
        for (int nj = 0; nj < 4; ++nj) {
            int c = wn + nj * 16 + l15;
            fbh[nj] = *reinterpret_cast<const bf16x8*>(&Bh[buf][c][lg * 8]);
            fbm[nj] = *reinterpret_cast<const bf16x8*>(&Bm[buf][c][lg * 8]);
            fbl[nj] = *reinterpret_cast<const bf16x8*>(&Bl[buf][c][lg * 8]);
        }
        // 96 MFMAs: 6 products per (mi,nj)
        #pragma unroll
        for (int mi = 0; mi < 4; ++mi)
            #pragma unroll
            for (int nj = 0; nj < 4; ++nj) {
                acc[mi][nj] = __builtin_amdgcn_mfma_f32_16x16x32_bf16(fah[mi], fbh[nj], acc[mi][nj], 0, 0, 0);
                acc[mi][nj] = __builtin_amdgcn_mfma_f32_16x16x32_bf16(fah[mi], fbm[nj], acc[mi][nj], 0, 0, 0);
                acc[mi][nj] = __builtin_amdgcn_mfma_f32_16x16x32_bf16(fam[mi], fbh[nj], acc[mi][nj], 0, 0, 0);
                acc[mi][nj] = __builtin_amdgcn_mfma_f32_16x16x32_bf16(fah[mi], fbl[nj], acc[mi][nj], 0, 0, 0);
                acc[mi][nj] = __builtin_amdgcn_mfma_f32_16x16x32_bf16(fam[mi], fbm[nj], acc[mi][nj], 0, 0, 0);
                acc[mi][nj] = __builtin_amdgcn_mfma_f32_16x16x32_bf16(fal[mi], fbh[nj], acc[mi][nj], 0, 0, 0);
            }
        __syncthreads();
    }

    // ---- epilogue: bias + exact GELU + dot W2; reduce 16 lanes then 4 waves ----
    float part[4][4];
    #pragma unroll
    for (int mi = 0; mi < 4; ++mi)
        #pragma unroll
        for (int r = 0; r < 4; ++r)
            part[mi][r] = 0.f;
    #pragma unroll
    for (int mi = 0; mi < 4; ++mi)
        #pragma unroll
        for (int nj = 0; nj < 4; ++nj)
            #pragma unroll
            for (int r = 0; r < 4; ++r) {
                float z = acc[mi][nj][r] + b1v[nj];
                float g = 0.5f * z * (1.0f + erff(z * 0.70710678118654752440f));
                part[mi][r] = fmaf(g, w2v[nj], part[mi][r]);
            }
    #pragma unroll
    for (int mi = 0; mi < 4; ++mi)
        #pragma unroll
        for (int r = 0; r < 4; ++r) {
            float v = part[mi][r];
            v += __shfl_xor(v, 1, 16);
            v += __shfl_xor(v, 2, 16);
            v += __shfl_xor(v, 4, 16);
            v += __shfl_xor(v, 8, 16);
            if (l15 == 0)
                red[wave & 3][wm + mi * 16 + lg * 4 + r] = v;
        }
    __syncthreads();
    if (tid < 128) {
        float s = red[0][tid] + red[1][tid] + red[2][tid] + red[3][tid];
        int grow = row0 + tid;
        logits[grow] = s + b2p[0] + base_logits[grow & (N_DIM - 1)];
    }
}

// ---------------- Kernel 2: softmax + top-8 + mask/importance/indices ----------------
__global__ __launch_bounds__(256) void softmax_topk_kernel(
    const float* __restrict__ logits,
    float* __restrict__ out_mask,
    float* __restrict__ out_importance,
    float* __restrict__ out_indices)
{
    const int b = blockIdx.x;
    const int tid = threadIdx.x;
    __shared__ float probs[N_DIM];
    __shared__ float redf[4];
    __shared__ int   redi[4];
    __shared__ int   sel_idx[K_SEL];

    float l0 = logits[b * N_DIM + tid];
    float l1 = logits[b * N_DIM + tid + 256];

    float m = fmaxf(l0, l1);
    #pragma unroll
    for (int s = 32; s >= 1; s >>= 1) m = fmaxf(m, __shfl_xor(m, s, 64));
    if ((tid & 63) == 0) redf[tid >> 6] = m;
    __syncthreads();
    float gm = fmaxf(fmaxf(redf[0], redf[1]), fmaxf(redf[2], redf[3]));
    __syncthreads();

    float e0 = expf(l0 - gm), e1 = expf(l1 - gm);
    float ssum = e0 + e1;
    #pragma unroll
    for (int s = 32; s >= 1; s >>= 1) ssum += __shfl_xor(ssum, s, 64);
    if ((tid & 63) == 0) redf[tid >> 6] = ssum;
    __syncthreads();
    float denom = redf[0] + redf[1] + redf[2] + redf[3];
    float p0 = e0 / denom, p1 = e1 / denom;
    probs[tid] = p0;
    probs[tid + 256] = p1;
    out_importance[b * N_DIM + tid] = p0;
    out_importance[b * N_DIM + tid + 256] = p1;
    __syncthreads();

    for (int it = 0; it < K_SEL; ++it) {
        float v0 = probs[tid]; int i0 = tid;
        float v1 = probs[tid + 256];
        if (v1 > v0) { v0 = v1; i0 = tid + 256; }
        #pragma unroll
        for (int s = 32; s >= 1; s >>= 1) {
            float ov = __shfl_xor(v0, s, 64);
            int   oi = __shfl_xor(i0, s, 64);
            if (ov > v0 || (ov == v0 && oi < i0)) { v0 = ov; i0 = oi; }
        }
        if ((tid & 63) == 0) { redf[tid >> 6] = v0; redi[tid >> 6] = i0; }
        __syncthreads();
        if (tid == 0) {
            float bv = redf[0]; int bi = redi[0];
            for (int w = 1; w < 4; ++w)
                if (redf[w] > bv || (redf[w] == bv && redi[w] < bi)) { bv = redf[w]; bi = redi[w]; }
            sel_idx[it] = bi;
            probs[bi] = -1.0f;
        }
        __syncthreads();
    }

    float mk0 = 0.f, mk1 = 0.f;
    #pragma unroll
    for (int i = 0; i < K_SEL; ++i) {
        if (sel_idx[i] == tid)       mk0 = 1.f;
        if (sel_idx[i] == tid + 256) mk1 = 1.f;
    }
    out_mask[b * N_DIM + tid] = mk0;
    out_mask[b * N_DIM + tid + 256] = mk1;

    if (tid < K_SEL) out_indices[b * K_SEL + tid] = (float)sel_idx[tid];
}

// ---------------- Kernel 3: gather selected rows (overwrites scratch last) ----------
__global__ __launch_bounds__(256) void gather_kernel(
    const float* __restrict__ X,
    const float* __restrict__ out_indices,
    float* __restrict__ out_selected)
{
    const int b = blockIdx.x;
    const int tid = threadIdx.x;
    __shared__ int sel[K_SEL];
    if (tid < K_SEL) sel[tid] = (int)out_indices[b * K_SEL + tid];
    __syncthreads();
    #pragma unroll
    for (int i = 0; i < 4; ++i) {
        int f = tid + 256 * i;
        int ki = f >> 7;
        int c4 = f & 127;
        float4 v = reinterpret_cast<const float4*>(
            X + ((size_t)b * N_DIM + sel[ki]) * D_DIM)[c4];
        reinterpret_cast<float4*>(
            out_selected + ((size_t)b * K_SEL + ki) * D_DIM)[c4] = v;
    }
}

extern "C" void kernel_launch(void* const* d_in, const int* in_sizes, int n_in,
                              void* d_out, int out_size, void* d_ws, size_t ws_size,
                              hipStream_t stream) {
    const float* X           = (const float*)d_in[0];
    const float* W1          = (const float*)d_in[1];
    const float* b1          = (const float*)d_in[2];
    const float* W2          = (const float*)d_in[3];
    const float* b2          = (const float*)d_in[4];
    const float* base_logits = (const float*)d_in[5];

    float* out            = (float*)d_out;
    float* out_selected   = out;                                  // 128*8*512 = 524288
    float* out_mask       = out_selected + B_DIM * K_SEL * D_DIM; // 128*512
    float* out_importance = out_mask + B_DIM * N_DIM;             // 128*512
    float* out_indices    = out_importance + B_DIM * N_DIM;       // 128*8

    // Scratch inside out_selected's region (gather overwrites it last):
    float*  logits = out_selected;                       // [0, 65536)
    __bf16* w1t_h  = (__bf16*)(out_selected + 65536);    // 131072 bf16
    __bf16* w1t_m  = (__bf16*)(out_selected + 131072);
    __bf16* w1t_l  = (__bf16*)(out_selected + 196608);

    hipLaunchKernelGGL(prep_w1_kernel, dim3(H_DIM), dim3(256), 0, stream,
                       W1, w1t_h, w1t_m, w1t_l);
    hipLaunchKernelGGL(fused_scorer_mfma, dim3((B_DIM * N_DIM) / 128), dim3(512), 0, stream,
                       X, w1t_h, w1t_m, w1t_l, b1, W2, b2, base_logits, logits);
    hipLaunchKernelGGL(softmax_topk_kernel, dim3(B_DIM), dim3(256), 0, stream,
                       logits, out_mask, out_importance, out_indices);
    hipLaunchKernelGGL(gather_kernel, dim3(B_DIM), dim3(256), 0, stream,
                       X, out_indices, out_selected);
}